// Round 14
// baseline (39.329 us; speedup 1.0000x reference)
//
#include <hip/hip_runtime.h>
#include <math.h>

// DegradedBicycleRollout: b=512, l=64, h=80, state=12.
// R14: fused dual-chain. R11/12/13 isolated: runtime ~ #chain-waves per CU
// (solo=22us, 2/CU=35us), independent of instruction count (R13's 60% instr
// offload = neutral) => chain wave is ~80% stall slots. Test+win: interleave
// TWO b's rollouts in ONE wave (2x ILP fills the stalls), exactly one chain
// wave per CU. grid=256 (1 block/CU), 4 waves: wv0 = dual chain, wv1-3 =
// flush both b's (16/48 slices each). LDS 2b x 2buf x 64 x 25 f4 = 102.4KB.

#define N_B 512
#define N_L 64
#define N_H 80
#define DT_F 0.1f
#define PITCH_F4 25       // 24 used + 1 pad
#define SPC 8             // steps per chunk
#define NCH 10            // chunks
#define INV2PI 0.15915494309189535f

__device__ __forceinline__ float fast_rcp(float x) { return __builtin_amdgcn_rcpf(x); }

__device__ __forceinline__ float fast_tanh(float x) {
    const float e2 = __expf(2.0f * x);
    return (e2 - 1.0f) * fast_rcp(e2 + 1.0f);
}

__device__ __forceinline__ float fast_sigmoid(float x) {
    return fast_rcp(1.0f + __expf(-x));
}

__device__ __forceinline__ float fast_atan_small(float z) {
    // |z| <= 0.42; odd Taylor through z^9, max err ~1e-5.
    const float z2 = z * z;
    float p = 1.0f / 9.0f;
    p = fmaf(p, z2, -1.0f / 7.0f);
    p = fmaf(p, z2, 1.0f / 5.0f);
    p = fmaf(p, z2, -1.0f / 3.0f);
    p = fmaf(p, z2, 1.0f);
    return z * p;
}

__device__ __forceinline__ float fast_tan_075(float x) {
    // tan(x) on |x|<=0.75, odd Taylor through x^13; max err ~3e-5 at edge.
    const float x2 = x * x;
    float p = 0.0035916f;
    p = fmaf(p, x2, 0.0088632f);
    p = fmaf(p, x2, 0.0218695f);
    p = fmaf(p, x2, 0.0539683f);
    p = fmaf(p, x2, 0.1333333f);
    p = fmaf(p, x2, 0.3333333f);
    return fmaf(p * x2, x, x);
}

struct Ctl { float delta, fb, fx, tan_d, beta, acc; };

__device__ __forceinline__ Ctl make_ctl(float u0, float u1, float u2,
                                        float steer_scale, float brake_scale,
                                        float throttle_scale, float neg_brake_lim) {
    Ctl t;
    t.delta = steer_scale * fast_tanh(u0);
    t.fb = brake_scale    * fast_sigmoid(u1);
    t.fx = throttle_scale * fast_sigmoid(u2);
    const float dc = fminf(fmaxf(t.delta, -0.75f), 0.75f);
    t.tan_d = fast_tan_075(dc);
    t.beta = fminf(fmaxf(fast_atan_small(0.45f * t.tan_d), -0.65f), 0.65f);
    t.acc = fminf(fmaxf(2.8f * t.fx - 6.5f * t.fb, neg_brake_lim), 3.0f);
    return t;
}

__global__ __launch_bounds__(256) void degraded_bicycle_rollout_kernel(
    const float* __restrict__ x0,        // [512,12]
    const float* __restrict__ controls,  // [512,64,80,3]
    const float* __restrict__ deg,       // [512,5]
    float* __restrict__ out)             // [512,64,81,12]
{
    __shared__ float4 outb[2][2][N_L * PITCH_F4];   // [bb][buf] 102.4 KB

    const int lane = threadIdx.x & 63;
    const int wv   = threadIdx.x >> 6;    // 0 = dual-chain, 1..3 = flushers
    const int b0 = blockIdx.x * 2;

    // flush slice set [S0,S1) of chunk FC; slice s -> bb=s/24, i=s%24
#define FLUSH_SLICES(FBUF, FC, S0, S1)                                            \
    {                                                                             \
        _Pragma("unroll")                                                         \
        for (int sl = (S0); sl < (S1); ++sl) {                                    \
            const int fbb = sl / 24;                                              \
            const int i = sl - fbb * 24;                                          \
            const size_t obase = (size_t)(b0 + fbb) * 62208 + 12                  \
                                 + (size_t)(FC) * (SPC * 12);                     \
            const unsigned flat = i * 64 + lane;                                  \
            const unsigned l = flat / 24u;                                        \
            const unsigned q = flat - l * 24u;                                    \
            const float4 v = outb[fbb][FBUF][l * PITCH_F4 + q];                   \
            *reinterpret_cast<float4*>(out + obase + (size_t)l * 972 + q * 4) = v;\
        }                                                                         \
    }

    if (wv == 0) {
        // ============== fused dual-chain persona ==============
        const float* dgA = deg + (b0 + 0) * 5;
        const float* dgB = deg + (b0 + 1) * 5;
        const float ssA = fmaxf(dgA[0], 0.05f), ssB = fmaxf(dgB[0], 0.05f);
        const float bsA = fmaxf(dgA[1], 0.05f), bsB = fmaxf(dgB[1], 0.05f);
        const float tsA = fmaxf(dgA[2], 0.05f), tsB = fmaxf(dgB[2], 0.05f);
        const float frA = fmaxf(dgA[4], 0.1f),  frB = fmaxf(dgB[4], 0.1f);
        const float nbA = -7.5f * frA, nbB = -7.5f * frB;
        const float ynA = frA * 9.81f, ynB = frB * 9.81f;
        const float inv_wb = 1.0f / 2.8f;

        const float4* xA = reinterpret_cast<const float4*>(x0 + (b0 + 0) * 12);
        const float4* xB = reinterpret_cast<const float4*>(x0 + (b0 + 1) * 12);
        const float4 a0 = xA[0], a1 = xA[1];
        const float4 b0v = xB[0], b1v = xB[1];

        float pxA = a0.x, pyA = a0.y, psiA = a0.z, vxA = a0.w, vyA = a1.x;
        float pxB = b0v.x, pyB = b0v.y, psiB = b0v.z, vxB = b0v.w, vyB = b1v.x;
        float sA = __builtin_amdgcn_sqrtf(fmaf(vxA, vxA, fmaf(vyA, vyA, 1e-6f)));
        float sB = __builtin_amdgcn_sqrtf(fmaf(vxB, vxB, fmaf(vyB, vyB, 1e-6f)));

        const float4* ucA = reinterpret_cast<const float4*>(controls + ((size_t)(b0 + 0) * 64 + lane) * 240);
        const float4* ucB = reinterpret_cast<const float4*>(controls + ((size_t)(b0 + 1) * 64 + lane) * 240);

        // prefetch group 0 for both b's
        float4 cA0 = ucA[0], cA1 = ucA[1], cA2 = ucA[2];
        float4 cB0 = ucB[0], cB1 = ucB[1], cB2 = ucB[2];

        for (int c = 0; c < NCH; ++c) {
            const int par = c & 1;
            float4* lrowA = &outb[0][par][lane * PITCH_F4];
            float4* lrowB = &outb[1][par][lane * PITCH_F4];

            #pragma unroll
            for (int gg = 0; gg < 2; ++gg) {   // 2 groups of 4 steps
                const int g = c * 2 + gg;
                float4 nA0 = cA0, nA1 = cA1, nA2 = cA2;
                float4 nB0 = cB0, nB1 = cB1, nB2 = cB2;
                if (g < 19) {
                    nA0 = ucA[(g + 1) * 3 + 0];
                    nA1 = ucA[(g + 1) * 3 + 1];
                    nA2 = ucA[(g + 1) * 3 + 2];
                    nB0 = ucB[(g + 1) * 3 + 0];
                    nB1 = ucB[(g + 1) * 3 + 1];
                    nB2 = ucB[(g + 1) * 3 + 2];
                }

                const Ctl tA0 = make_ctl(cA0.x, cA0.y, cA0.z, ssA, bsA, tsA, nbA);
                const Ctl tB0 = make_ctl(cB0.x, cB0.y, cB0.z, ssB, bsB, tsB, nbB);
                const Ctl tA1 = make_ctl(cA0.w, cA1.x, cA1.y, ssA, bsA, tsA, nbA);
                const Ctl tB1 = make_ctl(cB0.w, cB1.x, cB1.y, ssB, bsB, tsB, nbB);
                const Ctl tA2 = make_ctl(cA1.z, cA1.w, cA2.x, ssA, bsA, tsA, nbA);
                const Ctl tB2 = make_ctl(cB1.z, cB1.w, cB2.x, ssB, bsB, tsB, nbB);
                const Ctl tA3 = make_ctl(cA2.y, cA2.z, cA2.w, ssA, bsA, tsA, nbA);
                const Ctl tB3 = make_ctl(cB2.y, cB2.z, cB2.w, ssB, bsB, tsB, nbB);

                // one step of one chain; two chains interleaved per step index
#define STEP1(T, S, PX, PY, PSI, VX, VY, YN, LROW, RR)                            \
                {                                                                 \
                    const float s2 = fmaxf(fmaf((T).acc, DT_F, S), 0.0f);         \
                    const float raw_yaw = s2 * inv_wb * (T).tan_d;                \
                    const float yaw_lim = fmaxf((YN) * fast_rcp(fmaxf(s2, 2.0f)), 0.15f); \
                    const float yaw_rate = fminf(fmaxf(raw_yaw, -1.0f), 1.0f) * yaw_lim; \
                    const float psi2 = fmaf(yaw_rate, DT_F, PSI);                 \
                    const float ang = (psi2 + (T).beta) * INV2PI;                 \
                    const float sn = __builtin_amdgcn_sinf(ang);                  \
                    const float cs = __builtin_amdgcn_cosf(ang);                  \
                    const float vx2 = s2 * cs;                                    \
                    const float vy2 = s2 * sn;                                    \
                    const float px2 = fmaf(vx2, DT_F, PX);                        \
                    const float py2 = fmaf(vy2, DT_F, PY);                        \
                    const float ax = (vx2 - (VX)) * 10.0f;                        \
                    const float ay = (vy2 - (VY)) * 10.0f;                        \
                    (LROW)[(RR) * 3 + 0] = make_float4(px2, py2, psi2, vx2);      \
                    (LROW)[(RR) * 3 + 1] = make_float4(vy2, yaw_rate, ax, ay);    \
                    (LROW)[(RR) * 3 + 2] = make_float4((T).beta, (T).delta, (T).fb, (T).fx); \
                    S = __builtin_amdgcn_sqrtf(fmaf(s2, s2, 1e-6f));              \
                    PX = px2; PY = py2; PSI = psi2; VX = vx2; VY = vy2;           \
                }

                STEP1(tA0, sA, pxA, pyA, psiA, vxA, vyA, ynA, lrowA, gg * 4 + 0)
                STEP1(tB0, sB, pxB, pyB, psiB, vxB, vyB, ynB, lrowB, gg * 4 + 0)
                STEP1(tA1, sA, pxA, pyA, psiA, vxA, vyA, ynA, lrowA, gg * 4 + 1)
                STEP1(tB1, sB, pxB, pyB, psiB, vxB, vyB, ynB, lrowB, gg * 4 + 1)
                STEP1(tA2, sA, pxA, pyA, psiA, vxA, vyA, ynA, lrowA, gg * 4 + 2)
                STEP1(tB2, sB, pxB, pyB, psiB, vxB, vyB, ynB, lrowB, gg * 4 + 2)
                STEP1(tA3, sA, pxA, pyA, psiA, vxA, vyA, ynA, lrowA, gg * 4 + 3)
                STEP1(tB3, sB, pxB, pyB, psiB, vxB, vyB, ynB, lrowB, gg * 4 + 3)
#undef STEP1

                cA0 = nA0; cA1 = nA1; cA2 = nA2;
                cB0 = nB0; cB1 = nB1; cB2 = nB2;
            }
            __syncthreads();   // chunk c staged (both b's)
        }
    } else {
        // ============== flusher personas (3 waves, both b's) ==============
        const int s0 = (wv - 1) * 16;     // 16 of 48 slices each
        {
            // h=0 rows: wv1 -> b0, wv2 -> b1 (one-time, prologue slack)
            if (wv <= 2) {
                const int bh = b0 + (wv - 1);
                const float4* x0v = reinterpret_cast<const float4*>(x0 + bh * 12);
                const float4 xq0 = x0v[0];
                const float4 xq1 = x0v[1];
                const float4 xq2 = x0v[2];
                #pragma unroll
                for (int i = 0; i < 3; ++i) {
                    const unsigned flat = i * 64 + lane;
                    const unsigned l = flat / 3u;
                    const unsigned q = flat - l * 3u;
                    const float4 v = (q == 0) ? xq0 : (q == 1) ? xq1 : xq2;
                    *reinterpret_cast<float4*>(out + (size_t)bh * 62208 + (size_t)l * 972 + q * 4) = v;
                }
            }
        }

        for (int c = 0; c < NCH; ++c) {
            __syncthreads();   // chunk c staged by chain wave
            // flush chunk c while chain computes c+1 (dbuf parity-safe:
            // chain reuses buf[c&1] at chunk c+2, after barrier c+1 which
            // we reach only after this flush completes)
            FLUSH_SLICES(c & 1, c, s0, s0 + 16)
        }
    }
#undef FLUSH_SLICES
}

extern "C" void kernel_launch(void* const* d_in, const int* in_sizes, int n_in,
                              void* d_out, int out_size, void* d_ws, size_t ws_size,
                              hipStream_t stream) {
    (void)in_sizes; (void)n_in; (void)d_ws; (void)ws_size; (void)out_size;
    const float* x0       = (const float*)d_in[0];
    const float* controls = (const float*)d_in[1];
    const float* deg      = (const float*)d_in[2];
    float* out            = (float*)d_out;

    dim3 grid(N_B / 2), block(256);           // 256 blocks (1/CU) x 4 waves
    hipLaunchKernelGGL(degraded_bicycle_rollout_kernel, grid, block, 0, stream,
                       x0, controls, deg, out);
}

// Round 15
// 35.569 us; speedup vs baseline: 1.1057x; 1.1057x over previous
//
#include <hip/hip_runtime.h>
#include <math.h>

// DegradedBicycleRollout: b=512, l=64, h=80, state=12.
// R15: HALVE transcendental count (10 -> 5 per step). All 14 prior rounds
// conserved per-CU trans ops and all landed ~35us (~46 trans-wave-ops/us/CU);
// R13 proved MOVING trans between waves is neutral -> cap is per-CU total.
// Changes vs R12 (structure identical: 256 blocks x 8 waves, 2 chain waves
// on SIMD 0/1, 6 writer waves):
//  (1) sqrt -> max(s2, 1e-3)            [err <= 4e-4]
//  (2) chain sin/cos -> incremental rotation by d=yaw_rate*dt (|d|<=0.48,
//      deg5/6 polys, drift ~1e-4 over 80 steps) combined with sin/cos(beta)
//      VALU polys (|beta| <= 0.3973; the +-0.65 clip is dead).
//  (3) tanh + 2 sigmoid rcps -> ONE combined rcp (P=a*b*c trick).

#define N_B 512
#define N_L 64
#define N_H 80
#define DT_F 0.1f
#define PITCH_F4 25       // 24 used + 1 pad
#define SPC 8             // steps per chunk
#define NCH 10            // chunks
#define INV2PI 0.15915494309189535f

__device__ __forceinline__ float fast_rcp(float x) { return __builtin_amdgcn_rcpf(x); }

__device__ __forceinline__ float fast_atan_small(float z) {
    // |z| <= 0.42; odd Taylor through z^9, max err ~1e-5.
    const float z2 = z * z;
    float p = 1.0f / 9.0f;
    p = fmaf(p, z2, -1.0f / 7.0f);
    p = fmaf(p, z2, 1.0f / 5.0f);
    p = fmaf(p, z2, -1.0f / 3.0f);
    p = fmaf(p, z2, 1.0f);
    return z * p;
}

__device__ __forceinline__ float fast_tan_075(float x) {
    // tan(x) on |x|<=0.75, odd Taylor through x^13; max err ~3e-5 at edge.
    const float x2 = x * x;
    float p = 0.0035916f;
    p = fmaf(p, x2, 0.0088632f);
    p = fmaf(p, x2, 0.0218695f);
    p = fmaf(p, x2, 0.0539683f);
    p = fmaf(p, x2, 0.1333333f);
    p = fmaf(p, x2, 0.3333333f);
    return fmaf(p * x2, x, x);
}

struct Ctl { float delta, fb, fx, tan_d, beta, acc, sb, cb; };

__device__ __forceinline__ Ctl make_ctl(float u0, float u1, float u2,
                                        float steer_scale, float brake_scale,
                                        float throttle_scale, float neg_brake_lim) {
    Ctl t;
    // one rcp for {tanh denom, sigmoid1 denom, sigmoid2 denom}
    const float e2 = __expf(2.0f * u0);       // trans 1
    const float eb = __expf(-u1);             // trans 2
    const float ec = __expf(-u2);             // trans 3
    const float a  = e2 + 1.0f;               // in (1, ~6e4]
    const float bd = 1.0f + eb;               // in (1, ~250]
    const float cd = 1.0f + ec;
    const float bc = bd * cd;
    const float invP = fast_rcp(a * bc);      // trans 4 (only rcp here)
    t.delta = steer_scale * ((e2 - 1.0f) * (invP * bc));
    t.fb = brake_scale    * (invP * (a * cd));
    t.fx = throttle_scale * (invP * (a * bd));

    const float dc = fminf(fmaxf(t.delta, -0.75f), 0.75f);
    t.tan_d = fast_tan_075(dc);
    const float z = 0.45f * t.tan_d;          // |z| <= 0.4192
    t.beta = fast_atan_small(z);              // |beta| <= 0.3973 (clip dead)

    // sin/cos(beta) via VALU polys (no trans)
    const float b2 = t.beta * t.beta;
    float ps = fmaf(b2, 1.0f / 120.0f, -1.0f / 6.0f);
    ps = fmaf(b2, ps, 1.0f);
    t.sb = t.beta * ps;                                   // err <= 3.3e-7
    float pcc = fmaf(b2, -1.0f / 720.0f, 1.0f / 24.0f);
    float pc  = fmaf(b2, pcc, -0.5f);
    t.cb = fmaf(b2, pc, 1.0f);                            // err <= 2e-8

    t.acc = fminf(fmaxf(2.8f * t.fx - 6.5f * t.fb, neg_brake_lim), 3.0f);
    return t;
}

__global__ __launch_bounds__(512) void degraded_bicycle_rollout_kernel(
    const float* __restrict__ x0,        // [512,12]
    const float* __restrict__ controls,  // [512,64,80,3]
    const float* __restrict__ deg,       // [512,5]
    float* __restrict__ out)             // [512,64,81,12]
{
    __shared__ float4 lds4[2][2][N_L * PITCH_F4];   // [bb][buf] 102.4 KB

    const int lane = threadIdx.x & 63;
    const int wv   = threadIdx.x >> 6;        // 0..7

    const bool is_compute = (wv < 2);
    const int bb   = is_compute ? wv : ((wv - 2) & 1);
    const int slot = is_compute ? 0  : ((wv - 2) >> 1);

    const int b = blockIdx.x * 2 + bb;
    const size_t out_b = (size_t)b * 62208;   // b*64*972 floats

#define FLUSH_SLICE(BB, FBUF, FC, I0, I1)                                         \
    {                                                                             \
        const size_t obase = out_b + 12 + (size_t)(FC) * (SPC * 12);              \
        _Pragma("unroll")                                                         \
        for (int i = (I0); i < (I1); ++i) {                                       \
            const unsigned flat = i * 64 + lane;                                  \
            const unsigned l = flat / 24u;                                        \
            const unsigned q = flat - l * 24u;                                    \
            const float4 v = lds4[BB][FBUF][l * PITCH_F4 + q];                    \
            *reinterpret_cast<float4*>(out + obase + (size_t)l * 972 + q * 4) = v;\
        }                                                                         \
    }

    if (is_compute) {
        // ================= chain persona (one per b) =================
        const float* dg = deg + b * 5;
        const float steer_scale    = fmaxf(dg[0], 0.05f);
        const float brake_scale    = fmaxf(dg[1], 0.05f);
        const float throttle_scale = fmaxf(dg[2], 0.05f);
        const float friction       = fmaxf(dg[4], 0.1f);

        const float4* x0v = reinterpret_cast<const float4*>(x0 + b * 12);
        const float4 xi0 = x0v[0];
        const float4 xi1 = x0v[1];

        float px  = xi0.x;
        float py  = xi0.y;
        float psi = xi0.z;
        float vxp = xi0.w;
        float vyp = xi1.x;
        float s = __builtin_amdgcn_sqrtf(fmaf(vxp, vxp, fmaf(vyp, vyp, 1e-6f)));
        // incremental sincos state (one-time trans)
        float sp = __builtin_amdgcn_sinf(psi * INV2PI);
        float cp = __builtin_amdgcn_cosf(psi * INV2PI);

        const float neg_brake_lim = -7.5f * friction;
        const float yaw_num = friction * 9.81f;
        const float inv_wheelbase = 1.0f / 2.8f;

        const int tid = b * 64 + lane;
        const float4* uc = reinterpret_cast<const float4*>(controls + (size_t)tid * 240);

        float4 c0 = uc[0];
        float4 c1 = uc[1];
        float4 c2 = uc[2];

        for (int c = 0; c < NCH; ++c) {       // 10 chunks x 8 steps
            float4* lrow = &lds4[bb][c & 1][lane * PITCH_F4];

            #pragma unroll
            for (int gg = 0; gg < 2; ++gg) {  // 2 groups of 4 steps
                const int g = c * 2 + gg;
                float4 n0 = c0, n1 = c1, n2 = c2;
                if (g < 19) {
                    n0 = uc[(g + 1) * 3 + 0];
                    n1 = uc[(g + 1) * 3 + 1];
                    n2 = uc[(g + 1) * 3 + 2];
                }

                const Ctl tA = make_ctl(c0.x, c0.y, c0.z, steer_scale, brake_scale, throttle_scale, neg_brake_lim);
                const Ctl tB = make_ctl(c0.w, c1.x, c1.y, steer_scale, brake_scale, throttle_scale, neg_brake_lim);
                const Ctl tC = make_ctl(c1.z, c1.w, c2.x, steer_scale, brake_scale, throttle_scale, neg_brake_lim);
                const Ctl tD = make_ctl(c2.y, c2.z, c2.w, steer_scale, brake_scale, throttle_scale, neg_brake_lim);

#define ROLL_STEP(T, RR)                                                          \
                {                                                                 \
                    const float s2 = fmaxf(fmaf((T).acc, DT_F, s), 0.0f);         \
                    const float raw_yaw = s2 * inv_wheelbase * (T).tan_d;         \
                    const float yaw_lim = fmaxf(yaw_num * fast_rcp(fmaxf(s2, 2.0f)), 0.15f); \
                    const float yaw_rate = fminf(fmaxf(raw_yaw, -1.0f), 1.0f) * yaw_lim; \
                    const float psi2 = fmaf(yaw_rate, DT_F, psi);                 \
                    /* rotate (sp,cp) by d = yaw_rate*dt via polys (no trans) */  \
                    const float d  = yaw_rate * DT_F;     /* |d| <= 0.48 */       \
                    const float d2 = d * d;                                       \
                    float qs = fmaf(d2, 1.0f / 120.0f, -1.0f / 6.0f);             \
                    const float sd = d * fmaf(d2, qs, 1.0f);                      \
                    float qc = fmaf(d2, -1.0f / 720.0f, 1.0f / 24.0f);            \
                    qc = fmaf(d2, qc, -0.5f);                                     \
                    const float cdd = fmaf(d2, qc, 1.0f);                         \
                    const float spn = fmaf(sp, cdd, cp * sd);                     \
                    const float cpn = fmaf(cp, cdd, -(sp * sd));                  \
                    /* angle add beta: sin/cos(psi2 + beta) */                    \
                    const float sn = fmaf(spn, (T).cb, cpn * (T).sb);             \
                    const float cs = fmaf(cpn, (T).cb, -(spn * (T).sb));          \
                    const float vx2 = s2 * cs;                                    \
                    const float vy2 = s2 * sn;                                    \
                    const float px2 = fmaf(vx2, DT_F, px);                        \
                    const float py2 = fmaf(vy2, DT_F, py);                        \
                    const float ax = (vx2 - vxp) * 10.0f;                         \
                    const float ay = (vy2 - vyp) * 10.0f;                         \
                    lrow[(RR) * 3 + 0] = make_float4(px2, py2, psi2, vx2);        \
                    lrow[(RR) * 3 + 1] = make_float4(vy2, yaw_rate, ax, ay);      \
                    lrow[(RR) * 3 + 2] = make_float4((T).beta, (T).delta, (T).fb, (T).fx); \
                    s = fmaxf(s2, 1e-3f);   /* ~= sqrt(s2^2 + 1e-6) */            \
                    px = px2; py = py2; psi = psi2; vxp = vx2; vyp = vy2;         \
                    sp = spn; cp = cpn;                                           \
                }

                ROLL_STEP(tA, gg * 4 + 0)
                ROLL_STEP(tB, gg * 4 + 1)
                ROLL_STEP(tC, gg * 4 + 2)
                ROLL_STEP(tD, gg * 4 + 3)
#undef ROLL_STEP

                c0 = n0; c1 = n1; c2 = n2;
            }
            __syncthreads();   // chunk c staged
        }
    } else {
        // ============ writer personas: 3 per b, 8 slices each ============
        const int i0 = slot * 8;
        if (slot == 0) {
            const float4* x0v = reinterpret_cast<const float4*>(x0 + b * 12);
            const float4 xq0 = x0v[0];
            const float4 xq1 = x0v[1];
            const float4 xq2 = x0v[2];
            #pragma unroll
            for (int i = 0; i < 3; ++i) {
                const unsigned flat = i * 64 + lane;
                const unsigned l = flat / 3u;
                const unsigned q = flat - l * 3u;
                const float4 v = (q == 0) ? xq0 : (q == 1) ? xq1 : xq2;
                *reinterpret_cast<float4*>(out + out_b + (size_t)l * 972 + q * 4) = v;
            }
        }

        for (int c = 0; c < NCH; ++c) {
            __syncthreads();   // chunk c staged by chain waves
            FLUSH_SLICE(bb, c & 1, c, i0, i0 + 8)
        }
    }
#undef FLUSH_SLICE
}

extern "C" void kernel_launch(void* const* d_in, const int* in_sizes, int n_in,
                              void* d_out, int out_size, void* d_ws, size_t ws_size,
                              hipStream_t stream) {
    (void)in_sizes; (void)n_in; (void)d_ws; (void)ws_size; (void)out_size;
    const float* x0       = (const float*)d_in[0];
    const float* controls = (const float*)d_in[1];
    const float* deg      = (const float*)d_in[2];
    float* out            = (float*)d_out;

    dim3 grid(N_B / 2), block(512);           // 256 blocks (1/CU) x 8 waves
    hipLaunchKernelGGL(degraded_bicycle_rollout_kernel, grid, block, 0, stream,
                       x0, controls, deg, out);
}